// Round 1
// baseline (633.586 us; speedup 1.0000x reference)
//
#include <hip/hip_runtime.h>

// Problem constants (from reference): B=8, C=4, H=W=512, K_ITERS=10, ALPHA=2
#define Wd 512
#define HWp 262144            // 512*512 = 2^18, elements per (b,c) plane
#define BC 32                 // B*C planes
#define NTOT 8388608          // B*C*H*W = 2^23

// red[] layout (floats): [0..31]=pmin  [32..63]=pmax  [64..95]=psum
//                        [96..127]=s   [128..159]=o   [160]=total

__global__ void init_bound_kernel(const float* __restrict__ pred,
                                  const int* __restrict__ target,
                                  float* __restrict__ bound,
                                  float* __restrict__ red)
{
    int idx = blockIdx.x * blockDim.x + threadIdx.x;
    if (blockIdx.x == 0) {
        int t = threadIdx.x;
        if (t < BC) {
            red[t]          = __int_as_float(0x7F800000); // pmin = +inf
            red[BC + t]     = 0.0f;                       // pmax (values >= 0)
            red[2*BC + t]   = 0.0f;                       // psum
            red[3*BC + t]   = 1.0f;                       // s (identity for iter 0)
            red[4*BC + t]   = 0.0f;                       // o
        } else if (t == BC) {
            red[5*BC] = 0.0f;                             // total accumulator
        }
    }
    if (idx < NTOT) {
        int c   = (idx >> 18) & 3;   // (idx / HW) % C
        int b   = idx >> 20;         // idx / (C*HW)
        int pix = idx & (HWp - 1);
        int t   = target[(b << 18) | pix];
        float oh = (t == c) ? 1.0f : 0.0f;
        float d  = pred[idx] - oh;
        bound[idx] = d * d;
    }
}

// Fused: affine-folded 5-point cross stencil + clamp + per-plane min/max/sum
__global__ __launch_bounds__(256) void stencil_kernel(const float* __restrict__ in,
                                                      float* __restrict__ out,
                                                      float* __restrict__ red)
{
    const int plane = blockIdx.y;
    const float s = red[3*BC + plane];
    const float o = red[4*BC + plane];
    const float* ip = in  + (size_t)plane * HWp;
    float*       op = out + (size_t)plane * HWp;

    float lmin = __int_as_float(0x7F800000);
    float lmax = 0.0f;
    float lsum = 0.0f;

    const int stride = gridDim.x * blockDim.x;
    for (int idx = blockIdx.x * blockDim.x + threadIdx.x; idx < HWp; idx += stride) {
        int h = idx >> 9;
        int w = idx & (Wd - 1);
        float sum = ip[idx];
        float cnt = 1.0f;
        if (w > 0)      { sum += ip[idx - 1];   cnt += 1.0f; }
        if (w < Wd - 1) { sum += ip[idx + 1];   cnt += 1.0f; }
        if (h > 0)      { sum += ip[idx - Wd];  cnt += 1.0f; }
        if (h < Wd - 1) { sum += ip[idx + Wd];  cnt += 1.0f; }
        float dil = 0.2f * (s * sum + o * cnt); // affine-folded depthwise conv
        float e   = fmaxf(dil - 0.5f, 0.0f);
        op[idx] = e;
        lmin = fminf(lmin, e);
        lmax = fmaxf(lmax, e);
        lsum += e;
    }

    // wave (64-lane) reduction
    for (int off = 32; off > 0; off >>= 1) {
        lmin = fminf(lmin, __shfl_down(lmin, off));
        lmax = fmaxf(lmax, __shfl_down(lmax, off));
        lsum += __shfl_down(lsum, off);
    }
    __shared__ float smin[4], smax[4], ssum[4];
    int wave = threadIdx.x >> 6;
    if ((threadIdx.x & 63) == 0) { smin[wave] = lmin; smax[wave] = lmax; ssum[wave] = lsum; }
    __syncthreads();
    if (threadIdx.x == 0) {
        float bmin = smin[0], bmax = smax[0], bsum = ssum[0];
        for (int i = 1; i < 4; i++) {
            bmin = fminf(bmin, smin[i]);
            bmax = fmaxf(bmax, smax[i]);
            bsum += ssum[i];
        }
        // values are >= 0: int compare == float compare on the bit patterns
        atomicMin((int*)&red[plane],       __float_as_int(bmin));
        atomicMax((int*)&red[BC + plane],  __float_as_int(bmax));
        atomicAdd(&red[2*BC + plane], bsum);
    }
}

// One block, 64 threads (lanes 0..31 handle the 32 planes)
__global__ void scalars_kernel(float* __restrict__ red, float* __restrict__ out, int k)
{
    int t = threadIdx.x;
    float contrib = 0.0f;
    if (t < BC) {
        float mn = red[t];
        float mx = red[BC + t];
        float sm = red[2*BC + t];
        float denom = mx - mn;
        float s, o;
        if (denom != 0.0f) { s = 1.0f / denom; o = -mn / denom; }
        else               { s = 1.0f;         o = 0.0f; }
        red[3*BC + t] = s;
        red[4*BC + t] = o;
        float w = (float)((k + 1) * (k + 1));
        // sum of normalized plane = s*sum_raw + o*N  (closed form)
        contrib = (s * sm + o * 262144.0f) * w;
        // reset reducers for next iteration
        red[t]        = __int_as_float(0x7F800000);
        red[BC + t]   = 0.0f;
        red[2*BC + t] = 0.0f;
    }
    for (int off = 32; off > 0; off >>= 1)
        contrib += __shfl_down(contrib, off);
    if (t == 0) {
        float tot = red[5*BC] + contrib;
        red[5*BC] = tot;
        if (k == 9) out[0] = tot / 8388608.0f;  // mean over B*C*H*W
    }
}

extern "C" void kernel_launch(void* const* d_in, const int* in_sizes, int n_in,
                              void* d_out, int out_size, void* d_ws, size_t ws_size,
                              hipStream_t stream)
{
    const float* pred  = (const float*)d_in[0];
    const int* target  = (const int*)d_in[1];   // int labels 0..3
    float* out = (float*)d_out;

    float* buf0 = (float*)d_ws;
    float* buf1 = buf0 + NTOT;
    float* red  = buf1 + NTOT;   // 161 floats of reduction state

    init_bound_kernel<<<(NTOT + 255) / 256, 256, 0, stream>>>(pred, target, buf0, red);

    float* a = buf0;
    float* b = buf1;
    for (int k = 0; k < 10; k++) {
        dim3 grid(32, BC);  // 32 blocks per plane, 32 planes
        stencil_kernel<<<grid, 256, 0, stream>>>(a, b, red);
        scalars_kernel<<<1, 64, 0, stream>>>(red, out, k);
        float* tmp = a; a = b; b = tmp;
    }
}

// Round 2
// 304.679 us; speedup vs baseline: 2.0795x; 2.0795x over previous
//
#include <hip/hip_runtime.h>

// Problem constants: B=8, C=4, H=W=512, K_ITERS=10, ALPHA=2
#define Wd 512
#define W4 128                // float4s per row
#define HWp 262144            // elements per (b,c) plane
#define BC 32                 // B*C planes
#define NTOT 8388608          // B*C*H*W

#define F_INF __int_as_float(0x7F800000)

// red[] layout (floats): [0..31]=pmin [32..63]=pmax [64..95]=psum
//                        [96..127]=s  [128..159]=o  [160]=total

__global__ void init_red_kernel(float* __restrict__ red)
{
    int t = threadIdx.x;
    if (t < BC) {
        red[t]        = F_INF;  // pmin
        red[BC + t]   = 0.0f;   // pmax (values >= 0)
        red[2*BC + t] = 0.0f;   // psum
    }
    if (t == 0) red[5*BC] = 0.0f;  // total
}

// bound = (pred - onehot)^2 at a float4 granule (plane-local float4 index v)
__device__ __forceinline__ float4 load_bound4(const float* __restrict__ pred,
                                              const int* __restrict__ target,
                                              int plane, int v)
{
    const int b = plane >> 2, c = plane & 3;
    float4 p = ((const float4*)(pred + (size_t)plane * HWp))[v];
    int4   t = ((const int4*)(target + (size_t)b * HWp))[v];
    float4 r;
    float dx = p.x - (t.x == c ? 1.0f : 0.0f);
    float dy = p.y - (t.y == c ? 1.0f : 0.0f);
    float dz = p.z - (t.z == c ? 1.0f : 0.0f);
    float dw = p.w - (t.w == c ? 1.0f : 0.0f);
    r.x = dx*dx; r.y = dy*dy; r.z = dz*dz; r.w = dw*dw;
    return r;
}

__device__ __forceinline__ float load_bound1(const float* __restrict__ pred,
                                             const int* __restrict__ target,
                                             int plane, int i)
{
    const int b = plane >> 2, c = plane & 3;
    float p = pred[(size_t)plane * HWp + i];
    int   t = target[(size_t)b * HWp + i];
    float d = p - (t == c ? 1.0f : 0.0f);
    return d * d;
}

template <bool FIRST>
__global__ __launch_bounds__(256) void stencil_kernel(const float* __restrict__ in,
                                                      float* __restrict__ out,
                                                      const float* __restrict__ pred,
                                                      const int* __restrict__ target,
                                                      float* __restrict__ red,
                                                      int store)
{
    const int plane = blockIdx.y;
    const int chunk = blockIdx.x;              // 16 rows per chunk
    float s = 1.0f, o = 0.0f;
    if (!FIRST) { s = red[3*BC + plane]; o = red[4*BC + plane]; }

    const float* ip = in  + (size_t)plane * HWp;
    float*       op = out + (size_t)plane * HWp;

    const int col4 = threadIdx.x & 127;        // float4 column 0..127
    const int rsub = threadIdx.x >> 7;         // 0..1

    float lmin = F_INF, lmax = 0.0f, lsum = 0.0f;

    const bool hasL = (col4 > 0);
    const bool hasR = (col4 < W4 - 1);

    #pragma unroll
    for (int p = 0; p < 8; p++) {
        const int row = chunk * 16 + p * 2 + rsub;
        const int v   = row * W4 + col4;       // plane-local float4 index
        const bool hasU = (row > 0);
        const bool hasD = (row < Wd - 1);

        float4 c4, u4, d4;
        float lft = 0.0f, rgt = 0.0f;
        if (FIRST) {
            c4 = load_bound4(pred, target, plane, v);
            u4 = hasU ? load_bound4(pred, target, plane, v - W4) : make_float4(0,0,0,0);
            d4 = hasD ? load_bound4(pred, target, plane, v + W4) : make_float4(0,0,0,0);
            if (hasL) lft = load_bound1(pred, target, plane, 4*v - 1);
            if (hasR) rgt = load_bound1(pred, target, plane, 4*v + 4);
        } else {
            c4 = ((const float4*)ip)[v];
            u4 = hasU ? ((const float4*)ip)[v - W4] : make_float4(0,0,0,0);
            d4 = hasD ? ((const float4*)ip)[v + W4] : make_float4(0,0,0,0);
            if (hasL) lft = ip[4*v - 1];
            if (hasR) rgt = ip[4*v + 4];
        }

        const float vc = (hasU ? 1.0f : 0.0f) + (hasD ? 1.0f : 0.0f);
        float4 sum, cnt;
        sum.x = c4.x + c4.y + u4.x + d4.x + lft;
        cnt.x = 2.0f + (hasL ? 1.0f : 0.0f) + vc;
        sum.y = c4.x + c4.y + c4.z + u4.y + d4.y;
        cnt.y = 3.0f + vc;
        sum.z = c4.y + c4.z + c4.w + u4.z + d4.z;
        cnt.z = 3.0f + vc;
        sum.w = c4.z + c4.w + rgt + u4.w + d4.w;
        cnt.w = 2.0f + (hasR ? 1.0f : 0.0f) + vc;

        float4 e;
        e.x = fmaxf(0.2f * (s * sum.x + o * cnt.x) - 0.5f, 0.0f);
        e.y = fmaxf(0.2f * (s * sum.y + o * cnt.y) - 0.5f, 0.0f);
        e.z = fmaxf(0.2f * (s * sum.z + o * cnt.z) - 0.5f, 0.0f);
        e.w = fmaxf(0.2f * (s * sum.w + o * cnt.w) - 0.5f, 0.0f);

        if (store) ((float4*)op)[v] = e;

        lmin = fminf(lmin, fminf(fminf(e.x, e.y), fminf(e.z, e.w)));
        lmax = fmaxf(lmax, fmaxf(fmaxf(e.x, e.y), fmaxf(e.z, e.w)));
        lsum += (e.x + e.y) + (e.z + e.w);
    }

    // wave (64-lane) reduction
    for (int off = 32; off > 0; off >>= 1) {
        lmin = fminf(lmin, __shfl_down(lmin, off));
        lmax = fmaxf(lmax, __shfl_down(lmax, off));
        lsum += __shfl_down(lsum, off);
    }
    __shared__ float smin[4], smax[4], ssum[4];
    const int wave = threadIdx.x >> 6;
    if ((threadIdx.x & 63) == 0) { smin[wave] = lmin; smax[wave] = lmax; ssum[wave] = lsum; }
    __syncthreads();
    if (threadIdx.x == 0) {
        float bmin = smin[0], bmax = smax[0], bsum = ssum[0];
        for (int i = 1; i < 4; i++) {
            bmin = fminf(bmin, smin[i]);
            bmax = fmaxf(bmax, smax[i]);
            bsum += ssum[i];
        }
        // nonnegative floats: int compare == float compare
        atomicMin((int*)&red[plane],      __float_as_int(bmin));
        atomicMax((int*)&red[BC + plane], __float_as_int(bmax));
        atomicAdd(&red[2*BC + plane], bsum);
    }
}

// One block, 64 threads
__global__ void scalars_kernel(float* __restrict__ red, float* __restrict__ out, int k)
{
    int t = threadIdx.x;
    float contrib = 0.0f;
    if (t < BC) {
        float mn = red[t];
        float mx = red[BC + t];
        float sm = red[2*BC + t];
        float denom = mx - mn;
        float s, o;
        if (denom != 0.0f) { s = 1.0f / denom; o = -mn / denom; }
        else               { s = 1.0f;         o = 0.0f; }
        red[3*BC + t] = s;
        red[4*BC + t] = o;
        float w = (float)((k + 1) * (k + 1));
        contrib = (s * sm + o * 262144.0f) * w;   // sum of normalized plane
        // reset reducers for next iteration
        red[t]        = F_INF;
        red[BC + t]   = 0.0f;
        red[2*BC + t] = 0.0f;
    }
    for (int off = 32; off > 0; off >>= 1)
        contrib += __shfl_down(contrib, off);
    if (t == 0) {
        float tot = red[5*BC] + contrib;
        red[5*BC] = tot;
        if (k == 9) out[0] = tot / 8388608.0f;
    }
}

extern "C" void kernel_launch(void* const* d_in, const int* in_sizes, int n_in,
                              void* d_out, int out_size, void* d_ws, size_t ws_size,
                              hipStream_t stream)
{
    const float* pred = (const float*)d_in[0];
    const int* target = (const int*)d_in[1];
    float* out = (float*)d_out;

    float* buf0 = (float*)d_ws;
    float* buf1 = buf0 + NTOT;
    float* red  = buf1 + NTOT;

    init_red_kernel<<<1, 64, 0, stream>>>(red);

    dim3 grid(32, BC);  // 32 row-chunks x 32 planes
    // k = 0: bound computed on the fly from pred/target
    stencil_kernel<true><<<grid, 256, 0, stream>>>(nullptr, buf0, pred, target, red, 1);
    scalars_kernel<<<1, 64, 0, stream>>>(red, out, 0);

    float* a = buf0;
    float* b = buf1;
    for (int k = 1; k < 10; k++) {
        stencil_kernel<false><<<grid, 256, 0, stream>>>(a, b, pred, target, red, (k < 9) ? 1 : 0);
        scalars_kernel<<<1, 64, 0, stream>>>(red, out, k);
        float* tmp = a; a = b; b = tmp;
    }
}